// Round 7
// baseline (101.712 us; speedup 1.0000x reference)
//
#include <hip/hip_runtime.h>
#include <math.h>

typedef __attribute__((ext_vector_type(8))) short short8v;   // 8 bf16 bits
typedef __attribute__((ext_vector_type(4))) float f32x4;     // 16x16 MFMA acc

__device__ __forceinline__ unsigned short f2bf(float x) {
    union { float f; unsigned u; } v; v.f = x;
    unsigned r = v.u + 0x7FFF + ((v.u >> 16) & 1);   // RNE
    return (unsigned short)(r >> 16);
}
__device__ __forceinline__ float bf2f(unsigned short u) {
    union { unsigned u; float f; } v; v.u = ((unsigned)u) << 16;
    return v.f;
}
__device__ __forceinline__ unsigned pack2bf(float a, float b) {
    return (unsigned)f2bf(a) | ((unsigned)f2bf(b) << 16);
}
__device__ __forceinline__ float fast_tanh(float x) {
    float e = __expf(2.0f * x);
    return 1.0f - 2.0f / (e + 1.0f);
}

// d_ws layout (bytes):
//   [0, 4096)      A      f32  [64][16]
//   [4096, 12288)  W1T32  bf16 [128 col][32 k]  k>=16 ZERO
//   [12288, 45056) W2T    bf16 [128 col][128 k]
//   [45056, 49152) W3T    bf16 [16 col][128 k]
#define WS_A    0
#define WS_W1   4096
#define WS_W2   12288
#define WS_W3   45056

// ---------------------------------------------------------------------------
// Prep (proven rounds 4/5): one block, 256 threads.
// ---------------------------------------------------------------------------
__global__ __launch_bounds__(256) void ce_prep_kernel(
    const int* __restrict__ pilot_pos,
    const float* __restrict__ decay_param,
    const float* __restrict__ window_logits,
    const float* __restrict__ W1, const float* __restrict__ W2,
    const float* __restrict__ W3,
    char* __restrict__ ws)
{
    __shared__ float win[8], Gr[64], Gi[64], wln[64], wrn[64];
    __shared__ int lefts[64], pos[8];
    int t = threadIdx.x;
    if (t < 8) {
        pos[t] = pilot_pos[t];
        win[t] = 1.0f / (1.0f + expf(-window_logits[t]));
    }
    __syncthreads();
    float decay = log1pf(expf(decay_param[0]));
    if (t < 64) {
        float gr = 0.f, gi = 0.f;
        #pragma unroll
        for (int n = 0; n < 8; ++n) {
            float ang = 6.283185307179586f * (float)(n * t) * (1.0f / 64.0f);
            gr += win[n] * cosf(ang);
            gi += win[n] * sinf(ang);
        }
        Gr[t] = gr * (1.0f / 64.0f);
        Gi[t] = gi * (1.0f / 64.0f);
        int lft = 0;
        #pragma unroll
        for (int p = 1; p < 8; ++p) if (pos[p] <= t) lft = p;
        if (lft > 6) lft = 6;
        float x0 = (float)pos[lft], x1 = (float)pos[lft + 1], fi = (float)t;
        float wl = expf(-decay * fabsf(fi - x0));
        float wr = expf(-decay * fabsf(x1 - fi));
        float wsum = wl + wr + 1e-12f;
        lefts[t] = lft; wln[t] = wl / wsum; wrn[t] = wr / wsum;
    }
    __syncthreads();
    if (t < 64) {
        float ar[8], ai[8];
        for (int p = 0; p < 8; ++p) { ar[p] = 0.f; ai[p] = 0.f; }
        for (int i = 0; i < 64; ++i) {
            int d = (i - t) & 63;
            float gr = Gr[d], gi = Gi[d];
            int lft = lefts[i];
            float wa = wln[i], wb = wrn[i];
            ar[lft]     += wa * gr;  ai[lft]     += wa * gi;
            ar[lft + 1] += wb * gr;  ai[lft + 1] += wb * gi;
        }
        float* A = (float*)(ws + WS_A);
        for (int p = 0; p < 8; ++p) {
            A[t * 16 + 2 * p]     = ar[p];
            A[t * 16 + 2 * p + 1] = ai[p];
        }
    }
    unsigned short* w1t = (unsigned short*)(ws + WS_W1);
    for (int i = t; i < 128 * 32; i += 256) {
        int col = i >> 5, k = i & 31;
        w1t[i] = (k < 16) ? f2bf(W1[k * 128 + col]) : (unsigned short)0;
    }
    unsigned short* w2t = (unsigned short*)(ws + WS_W2);
    for (int i = t; i < 128 * 128; i += 256) {
        int col = i >> 7, k = i & 127;
        w2t[i] = f2bf(W2[k * 128 + col]);
    }
    unsigned short* w3t = (unsigned short*)(ws + WS_W3);
    for (int i = t; i < 16 * 128; i += 256) {
        int col = i >> 7, k = i & 127;
        w3t[i] = f2bf(W3[k * 64 + col]);
    }
}

// ---------------------------------------------------------------------------
// Main: 256 thr = 4 waves (PROVEN geometry), 32 elements/wave via dual tiles
// (T0: lanes kg<2, T1: lanes kg>=2 provide LS; MFMA fragments shared/swapped).
// MFMAs use operand-swapped form: mfma(Wfrag, xfrag) -> C rows = W-cols,
// C cols = elements; each lane's 4 outputs are 4 consecutive LDS shorts
// -> packed ds_write_b64 writebacks. Same verified 16x16x32 layouts.
// ---------------------------------------------------------------------------
__global__ __launch_bounds__(256, 2) void ce_main(
    const float* __restrict__ Y, const float* __restrict__ Xp,
    const int* __restrict__ pilot_pos,
    const float* __restrict__ b1, const float* __restrict__ b2,
    const float* __restrict__ b3,
    const float* __restrict__ est_w, const float* __restrict__ alpha,
    const char* __restrict__ ws,
    float* __restrict__ out, int B)
{
    __shared__ unsigned short sH[4][16 * 136];   // 17408 B (per-wave, reused T0->T1)
    __shared__ float sLS[128 * 16];              // 8192 B
    __shared__ unsigned short sO[128 * 16];      // 4096 B

    const unsigned short* w1t = (const unsigned short*)(ws + WS_W1);
    const unsigned short* w2t = (const unsigned short*)(ws + WS_W2);
    const unsigned short* w3t = (const unsigned short*)(ws + WS_W3);
    const float* Amat = (const float*)(ws + WS_A);

    const int t = threadIdx.x;
    const int w = t >> 6, l = t & 63;
    const int m = l & 15, kg = l >> 4;
    const int tl = kg >> 1;        // which tile this lane's LS serves
    const int pg = kg & 1;         // pilot group (0: p0-3, 1: p4-7)

    // ---- LS: every lane computes 4 pilots of one element ----
    const int e_ls = w * 32 + tl * 16 + m;       // element within block
    long eg = (long)blockIdx.x * 128 + e_ls;
    long egc = (eg < B) ? eg : (long)(B - 1);
    short8v a1;
    {
        int p0 = pg * 4;
        const float* yrow = Y + egc * 128;
        const float4* xr = (const float4*)(Xp + egc * 16 + pg * 8);
        float4 x0 = xr[0], x1 = xr[1];
        float2 y0 = *(const float2*)(yrow + pilot_pos[p0 + 0] * 2);
        float2 y1 = *(const float2*)(yrow + pilot_pos[p0 + 1] * 2);
        float2 y2 = *(const float2*)(yrow + pilot_pos[p0 + 2] * 2);
        float2 y3 = *(const float2*)(yrow + pilot_pos[p0 + 3] * 2);
        float ls[8], inv;
        inv = 1.0f / (x0.x * x0.x + x0.y * x0.y);
        ls[0] = (y0.x * x0.x + y0.y * x0.y) * inv;
        ls[1] = (y0.y * x0.x - y0.x * x0.y) * inv;
        inv = 1.0f / (x0.z * x0.z + x0.w * x0.w);
        ls[2] = (y1.x * x0.z + y1.y * x0.w) * inv;
        ls[3] = (y1.y * x0.z - y1.x * x0.w) * inv;
        inv = 1.0f / (x1.x * x1.x + x1.y * x1.y);
        ls[4] = (y2.x * x1.x + y2.y * x1.y) * inv;
        ls[5] = (y2.y * x1.x - y2.x * x1.y) * inv;
        inv = 1.0f / (x1.z * x1.z + x1.w * x1.w);
        ls[6] = (y3.x * x1.z + y3.y * x1.w) * inv;
        ls[7] = (y3.y * x1.z - y3.x * x1.w) * inv;
        float4 s0 = { ls[0], ls[1], ls[2], ls[3] };
        float4 s1 = { ls[4], ls[5], ls[6], ls[7] };
        *(float4*)(sLS + e_ls * 16 + pg * 8)     = s0;
        *(float4*)(sLS + e_ls * 16 + pg * 8 + 4) = s1;
        #pragma unroll
        for (int e = 0; e < 8; ++e) a1[e] = (short)f2bf(ls[e]);
    }
    // T0's B-frag: lanes kg<2 hold T0 data (k=pg*8+e); kg>=2 hold T1 data,
    // multiplied by ZERO A rows (w1t k>=16) -> harmless. T1's B-frag: swap halves.
    short8v a1s;
    {
        union { short8v v; int i[4]; } ua, ub;
        ua.v = a1;
        #pragma unroll
        for (int q = 0; q < 4; ++q) ub.i[q] = __shfl_xor(ua.i[q], 32);
        a1s = ub.v;
    }

    const f32x4 z4 = {0.f, 0.f, 0.f, 0.f};
    unsigned short* hw = sH[w];
    const int wcol4 = kg * 4;   // this lane's 4-consecutive output-col base offset

    #pragma unroll
    for (int tile = 0; tile < 2; ++tile) {
        const short8v bx = tile ? a1s : a1;
        const int ebase = w * 32 + tile * 16;

        // ---- Layer 1: C[w1col][elem], packed b64 writeback ----
        #pragma unroll
        for (int ct = 0; ct < 8; ++ct) {
            short8v wf = *(const short8v*)(w1t + (ct * 16 + m) * 32 + kg * 8);
            f32x4 acc = __builtin_amdgcn_mfma_f32_16x16x32_bf16(wf, bx, z4, 0, 0, 0);
            float4 bv = *(const float4*)(b1 + ct * 16 + wcol4);
            float v0 = fmaxf(acc[0] + bv.x, 0.f), v1 = fmaxf(acc[1] + bv.y, 0.f);
            float v2 = fmaxf(acc[2] + bv.z, 0.f), v3 = fmaxf(acc[3] + bv.w, 0.f);
            uint2 u = { pack2bf(v0, v1), pack2bf(v2, v3) };
            *(uint2*)(hw + m * 136 + ct * 16 + wcol4) = u;
        }
        __syncthreads();

        // ---- Layer 2: A=W2frag, B=H(elem m) ----
        f32x4 acc2[8];
        #pragma unroll
        for (int ct = 0; ct < 8; ++ct) acc2[ct] = z4;
        #pragma unroll
        for (int ks = 0; ks < 4; ++ks) {
            int ch = ks * 4 + kg;
            short8v af = *(const short8v*)(hw + m * 136 + ch * 8);
            #pragma unroll
            for (int ct = 0; ct < 8; ++ct) {
                short8v wf = *(const short8v*)(w2t + (ct * 16 + m) * 128 + ch * 8);
                acc2[ct] = __builtin_amdgcn_mfma_f32_16x16x32_bf16(wf, af, acc2[ct], 0, 0, 0);
            }
        }
        __syncthreads();   // sH reads done before overwrite
        #pragma unroll
        for (int ct = 0; ct < 8; ++ct) {
            float4 bv = *(const float4*)(b2 + ct * 16 + wcol4);
            float v0 = fmaxf(acc2[ct][0] + bv.x, 0.f), v1 = fmaxf(acc2[ct][1] + bv.y, 0.f);
            float v2 = fmaxf(acc2[ct][2] + bv.z, 0.f), v3 = fmaxf(acc2[ct][3] + bv.w, 0.f);
            uint2 u = { pack2bf(v0, v1), pack2bf(v2, v3) };
            *(uint2*)(hw + m * 136 + ct * 16 + wcol4) = u;
        }
        __syncthreads();

        // ---- Layer 3: A=W3frag (16 cols), B=H ----
        f32x4 acc3 = z4;
        #pragma unroll
        for (int ks = 0; ks < 4; ++ks) {
            int ch = ks * 4 + kg;
            short8v af = *(const short8v*)(hw + m * 136 + ch * 8);
            short8v wf = *(const short8v*)(w3t + m * 128 + ch * 8);
            acc3 = __builtin_amdgcn_mfma_f32_16x16x32_bf16(wf, af, acc3, 0, 0, 0);
        }
        {   // lane holds outputs wcol4..wcol4+3 of element (ebase+m)
            uint2 u = { pack2bf(acc3[0], acc3[1]), pack2bf(acc3[2], acc3[3]) };
            *(uint2*)(sO + (ebase + m) * 16 + wcol4) = u;
        }
        __syncthreads();   // also protects sH before next tile's L1 overwrite
    }

    // ---- comb: lane -> element l>>1 (32/wave), half qh = l&1 (4 pilots) ----
    float w0 = est_w[0];
    float al = fminf(fmaxf(alpha[0], 0.f), 1.f);
    float oma = 1.0f - al;
    {
        int e2 = w * 32 + (l >> 1), qh = l & 1;
        float* lsp = sLS + e2 * 16 + qh * 8;
        float4 lv0 = *(float4*)(lsp);
        float4 lv1 = *(float4*)(lsp + 4);
        float lvv[8] = { lv0.x, lv0.y, lv0.z, lv0.w, lv1.x, lv1.y, lv1.z, lv1.w };
        const unsigned short* op = sO + e2 * 16;
        float cb[8];
        #pragma unroll
        for (int d = 0; d < 4; ++d) {
            int p = 4 * qh + d;
            float o_r = bf2f(op[p])     + b3[p];
            float o_i = bf2f(op[8 + p]) + b3[8 + p];
            cb[2 * d]     = al * (lvv[2 * d] * w0)     + oma * fast_tanh(o_r);
            cb[2 * d + 1] = al * (lvv[2 * d + 1] * w0) + oma * fast_tanh(o_i);
        }
        float4 c0 = { cb[0], cb[1], cb[2], cb[3] };
        float4 c1 = { cb[4], cb[5], cb[6], cb[7] };
        *(float4*)(lsp)     = c0;
        *(float4*)(lsp + 4) = c1;
    }
    __syncthreads();

    // ---- epilogue: per instr the wave writes 1 KB contiguous (2 elems) ----
    {
        int j = l & 31, half = l >> 5;
        float Ar[32];
        const float4* ap = (const float4*)(Amat + j * 32);
        #pragma unroll
        for (int q4 = 0; q4 < 8; ++q4) {
            float4 v = ap[q4];
            Ar[4 * q4 + 0] = v.x; Ar[4 * q4 + 1] = v.y;
            Ar[4 * q4 + 2] = v.z; Ar[4 * q4 + 3] = v.w;
        }
        #pragma unroll
        for (int it = 0; it < 16; ++it) {
            int e2 = w * 32 + 2 * it + half;
            long gelem = (long)blockIdx.x * 128 + e2;
            const float* lsp = sLS + e2 * 16;
            float4 C0 = *(const float4*)(lsp + 0), C1 = *(const float4*)(lsp + 4);
            float4 C2 = *(const float4*)(lsp + 8), C3 = *(const float4*)(lsp + 12);
            float cr[8] = { C0.x, C0.z, C1.x, C1.z, C2.x, C2.z, C3.x, C3.z };
            float ci[8] = { C0.y, C0.w, C1.y, C1.w, C2.y, C2.w, C3.y, C3.w };
            float hr0 = 0.f, hi0 = 0.f, hr1 = 0.f, hi1 = 0.f;
            #pragma unroll
            for (int p = 0; p < 8; ++p) {
                float a0r = Ar[2 * p], a0i = Ar[2 * p + 1];
                float a1r = Ar[16 + 2 * p], a1i = Ar[17 + 2 * p];
                hr0 += cr[p] * a0r - ci[p] * a0i;
                hi0 += cr[p] * a0i + ci[p] * a0r;
                hr1 += cr[p] * a1r - ci[p] * a1i;
                hi1 += cr[p] * a1i + ci[p] * a1r;
            }
            if (gelem < B) {
                float4 st = { hr0, hi0, hr1, hi1 };
                *(float4*)(out + gelem * 128 + j * 4) = st;
            }
        }
    }
}

extern "C" void kernel_launch(void* const* d_in, const int* in_sizes, int n_in,
                              void* d_out, int out_size, void* d_ws, size_t ws_size,
                              hipStream_t stream) {
    const float* Y             = (const float*)d_in[0];
    const float* Xp            = (const float*)d_in[1];
    const int*   pilot_pos     = (const int*)d_in[2];
    const float* W1            = (const float*)d_in[3];
    const float* b1            = (const float*)d_in[4];
    const float* W2            = (const float*)d_in[5];
    const float* b2            = (const float*)d_in[6];
    const float* W3            = (const float*)d_in[7];
    const float* b3            = (const float*)d_in[8];
    const float* est_w         = (const float*)d_in[9];
    const float* alpha         = (const float*)d_in[10];
    const float* decay_param   = (const float*)d_in[11];
    const float* window_logits = (const float*)d_in[12];
    float* out = (float*)d_out;
    char* ws = (char*)d_ws;

    int B = in_sizes[0] / 128;

    hipLaunchKernelGGL(ce_prep_kernel, dim3(1), dim3(256), 0, stream,
                       pilot_pos, decay_param, window_logits, W1, W2, W3, ws);
    int grid = (B + 127) / 128;
    hipLaunchKernelGGL(ce_main, dim3(grid), dim3(256), 0, stream,
                       Y, Xp, pilot_pos, b1, b2, b3, est_w, alpha,
                       ws, out, B);
}

// Round 8
// 93.792 us; speedup vs baseline: 1.0844x; 1.0844x over previous
//
#include <hip/hip_runtime.h>
#include <math.h>

typedef __attribute__((ext_vector_type(8))) short short8v;   // 8 bf16 bits
typedef __attribute__((ext_vector_type(4))) float f32x4;     // 16x16 MFMA acc

__device__ __forceinline__ unsigned short f2bf(float x) {
    union { float f; unsigned u; } v; v.f = x;
    unsigned r = v.u + 0x7FFF + ((v.u >> 16) & 1);   // RNE
    return (unsigned short)(r >> 16);
}
__device__ __forceinline__ float bf2f(unsigned short u) {
    union { unsigned u; float f; } v; v.u = ((unsigned)u) << 16;
    return v.f;
}
__device__ __forceinline__ unsigned pack2bf(float a, float b) {
    return (unsigned)f2bf(a) | ((unsigned)f2bf(b) << 16);
}
__device__ __forceinline__ float fast_tanh(float x) {
    float e = __expf(2.0f * x);
    return 1.0f - 2.0f / (e + 1.0f);
}

// sigma: output-dim permutation making L1->L2 and L2->L3 handoffs register-local.
// sigma(ct,p) = 32*(ct>>1) + 8*(p>>2) + 4*(ct&1) + (p&3)  — bijection on 0..127.
__device__ __host__ __forceinline__ int sigma_perm(int ct, int p) {
    return 32 * (ct >> 1) + 8 * (p >> 2) + 4 * (ct & 1) + (p & 3);
}

// d_ws layout (bytes):
//   [0, 4096)      A      f32  [64][16]
//   [4096, 12288)  W1P    bf16 [8 ct][16 row][32 k]  k>=16 ZERO, rows sigma-permuted
//   [12288, 45056) W2P    bf16 [8 ct][16 row][128 k] rows sigma-permuted
//   [45056, 49152) W3T    bf16 [16 col][128 k]       canonical
#define WS_A    0
#define WS_W1   4096
#define WS_W2   12288
#define WS_W3   45056

// ---------------------------------------------------------------------------
// Prep: one block, 256 threads. A-build proven (rounds 1-7).
// ---------------------------------------------------------------------------
__global__ __launch_bounds__(256) void ce_prep_kernel(
    const int* __restrict__ pilot_pos,
    const float* __restrict__ decay_param,
    const float* __restrict__ window_logits,
    const float* __restrict__ W1, const float* __restrict__ W2,
    const float* __restrict__ W3,
    char* __restrict__ ws)
{
    __shared__ float win[8], Gr[64], Gi[64], wln[64], wrn[64];
    __shared__ int lefts[64], pos[8];
    int t = threadIdx.x;
    if (t < 8) {
        pos[t] = pilot_pos[t];
        win[t] = 1.0f / (1.0f + expf(-window_logits[t]));
    }
    __syncthreads();
    float decay = log1pf(expf(decay_param[0]));
    if (t < 64) {
        float gr = 0.f, gi = 0.f;
        #pragma unroll
        for (int n = 0; n < 8; ++n) {
            float ang = 6.283185307179586f * (float)(n * t) * (1.0f / 64.0f);
            gr += win[n] * cosf(ang);
            gi += win[n] * sinf(ang);
        }
        Gr[t] = gr * (1.0f / 64.0f);
        Gi[t] = gi * (1.0f / 64.0f);
        int lft = 0;
        #pragma unroll
        for (int p = 1; p < 8; ++p) if (pos[p] <= t) lft = p;
        if (lft > 6) lft = 6;
        float x0 = (float)pos[lft], x1 = (float)pos[lft + 1], fi = (float)t;
        float wl = expf(-decay * fabsf(fi - x0));
        float wr = expf(-decay * fabsf(x1 - fi));
        float wsum = wl + wr + 1e-12f;
        lefts[t] = lft; wln[t] = wl / wsum; wrn[t] = wr / wsum;
    }
    __syncthreads();
    if (t < 64) {
        float ar[8], ai[8];
        for (int p = 0; p < 8; ++p) { ar[p] = 0.f; ai[p] = 0.f; }
        for (int i = 0; i < 64; ++i) {
            int d = (i - t) & 63;
            float gr = Gr[d], gi = Gi[d];
            int lft = lefts[i];
            float wa = wln[i], wb = wrn[i];
            ar[lft]     += wa * gr;  ai[lft]     += wa * gi;
            ar[lft + 1] += wb * gr;  ai[lft + 1] += wb * gi;
        }
        float* A = (float*)(ws + WS_A);
        for (int p = 0; p < 8; ++p) {
            A[t * 16 + 2 * p]     = ar[p];
            A[t * 16 + 2 * p + 1] = ai[p];
        }
    }
    // W1P: [ct][row][32 k], entry = W1[k][sigma(ct,row)] for k<16 else 0
    unsigned short* w1p = (unsigned short*)(ws + WS_W1);
    for (int i = t; i < 128 * 32; i += 256) {
        int row = i >> 5, k = i & 31;
        int ct = row >> 4, p = row & 15;
        w1p[i] = (k < 16) ? f2bf(W1[k * 128 + sigma_perm(ct, p)]) : (unsigned short)0;
    }
    // W2P: [ct][row][128 k], entry = W2[k][sigma(ct,row)]
    unsigned short* w2p = (unsigned short*)(ws + WS_W2);
    for (int i = t; i < 128 * 128; i += 256) {
        int row = i >> 7, k = i & 127;
        int ct = row >> 4, p = row & 15;
        w2p[i] = f2bf(W2[k * 128 + sigma_perm(ct, p)]);
    }
    // W3T canonical: [16 col][128 k]
    unsigned short* w3t = (unsigned short*)(ws + WS_W3);
    for (int i = t; i < 16 * 128; i += 256) {
        int col = i >> 7, k = i & 127;
        w3t[i] = f2bf(W3[k * 64 + col]);
    }
}

// ---------------------------------------------------------------------------
// Main: 256 thr = 4 waves, 16 elems/wave, 64 elems/block (proven geometry).
// Whole MLP is register-resident per wave: sigma-permuted weight tables make
// each layer's C output exactly the next layer's B fragment after an
// in-register relu+pack — no LDS, no shuffles, no barriers inside the MLP.
// MFMA orientation mfma(Wfrag, xfrag) proven in round 7; LS/comb/epilogue
// proven in round 5. Only 2 barriers per kernel, all dataflow intra-wave.
// ---------------------------------------------------------------------------
__global__ __launch_bounds__(256) void ce_main(
    const float* __restrict__ Y, const float* __restrict__ Xp,
    const int* __restrict__ pilot_pos,
    const float* __restrict__ b1, const float* __restrict__ b2,
    const float* __restrict__ b3,
    const float* __restrict__ est_w, const float* __restrict__ alpha,
    const char* __restrict__ ws,
    float* __restrict__ out, int B)
{
    __shared__ float sLS[64 * 16];            // 4096 B
    __shared__ unsigned short sO[64 * 16];    // 2048 B

    const unsigned short* w1p = (const unsigned short*)(ws + WS_W1);
    const unsigned short* w2p = (const unsigned short*)(ws + WS_W2);
    const unsigned short* w3t = (const unsigned short*)(ws + WS_W3);
    const float* Amat = (const float*)(ws + WS_A);

    const int t = threadIdx.x;
    const int w = t >> 6, l = t & 63;
    const int m = l & 15, kg = l >> 4;
    const int e_loc = w * 16 + m;
    long eg = (long)blockIdx.x * 64 + e_loc;
    long egc = (eg < B) ? eg : (long)(B - 1);

    // ---- LS (round-5 proven): lanes kg<2 compute pilots [4kg,4kg+4) ----
    short8v xb = {0, 0, 0, 0, 0, 0, 0, 0};
    if (kg < 2) {
        const float* yrow = Y + egc * 128;
        const float4* xr = (const float4*)(Xp + egc * 16 + kg * 8);
        float4 x0 = xr[0], x1 = xr[1];
        int p0 = kg * 4;
        float2 y0 = *(const float2*)(yrow + pilot_pos[p0 + 0] * 2);
        float2 y1 = *(const float2*)(yrow + pilot_pos[p0 + 1] * 2);
        float2 y2 = *(const float2*)(yrow + pilot_pos[p0 + 2] * 2);
        float2 y3 = *(const float2*)(yrow + pilot_pos[p0 + 3] * 2);
        float ls[8], inv;
        inv = 1.0f / (x0.x * x0.x + x0.y * x0.y);
        ls[0] = (y0.x * x0.x + y0.y * x0.y) * inv;
        ls[1] = (y0.y * x0.x - y0.x * x0.y) * inv;
        inv = 1.0f / (x0.z * x0.z + x0.w * x0.w);
        ls[2] = (y1.x * x0.z + y1.y * x0.w) * inv;
        ls[3] = (y1.y * x0.z - y1.x * x0.w) * inv;
        inv = 1.0f / (x1.x * x1.x + x1.y * x1.y);
        ls[4] = (y2.x * x1.x + y2.y * x1.y) * inv;
        ls[5] = (y2.y * x1.x - y2.x * x1.y) * inv;
        inv = 1.0f / (x1.z * x1.z + x1.w * x1.w);
        ls[6] = (y3.x * x1.z + y3.y * x1.w) * inv;
        ls[7] = (y3.y * x1.z - y3.x * x1.w) * inv;
        float4 s0 = { ls[0], ls[1], ls[2], ls[3] };
        float4 s1 = { ls[4], ls[5], ls[6], ls[7] };
        *(float4*)(sLS + e_loc * 16 + kg * 8)     = s0;
        *(float4*)(sLS + e_loc * 16 + kg * 8 + 4) = s1;
        #pragma unroll
        for (int e = 0; e < 8; ++e) xb[e] = (short)f2bf(ls[e]);
    }

    const f32x4 z4 = {0.f, 0.f, 0.f, 0.f};
    typedef union { unsigned u[4]; short8v v; } pk_t;

    // ---- Layer 1 (8 MFMA) + in-register repack ----
    pk_t h1[4];
    #pragma unroll
    for (int ks = 0; ks < 4; ++ks) {
        #pragma unroll
        for (int half = 0; half < 2; ++half) {
            int ct = 2 * ks + half;
            short8v wf = *(const short8v*)(w1p + (ct * 16 + m) * 32 + kg * 8);
            f32x4 acc = __builtin_amdgcn_mfma_f32_16x16x32_bf16(wf, xb, z4, 0, 0, 0);
            // bias at sigma(ct, 4kg+r) = 32ks + 8kg + 4half + r
            float4 bv = *(const float4*)(b1 + ks * 32 + kg * 8 + half * 4);
            float v0 = fmaxf(acc[0] + bv.x, 0.f), v1 = fmaxf(acc[1] + bv.y, 0.f);
            float v2 = fmaxf(acc[2] + bv.z, 0.f), v3 = fmaxf(acc[3] + bv.w, 0.f);
            h1[ks].u[2 * half]     = pack2bf(v0, v1);
            h1[ks].u[2 * half + 1] = pack2bf(v2, v3);
        }
    }

    // ---- Layer 2 (32 MFMA), K=128 in 4 steps, h1 as B fragments ----
    f32x4 acc2[8];
    #pragma unroll
    for (int ct = 0; ct < 8; ++ct) acc2[ct] = z4;
    #pragma unroll
    for (int ks = 0; ks < 4; ++ks) {
        short8v hf = h1[ks].v;
        #pragma unroll
        for (int ct = 0; ct < 8; ++ct) {
            short8v wf = *(const short8v*)(w2p + (ct * 16 + m) * 128 + ks * 32 + kg * 8);
            acc2[ct] = __builtin_amdgcn_mfma_f32_16x16x32_bf16(wf, hf, acc2[ct], 0, 0, 0);
        }
    }

    // ---- repack L2 -> h2 ----
    pk_t h2[4];
    #pragma unroll
    for (int ks = 0; ks < 4; ++ks) {
        #pragma unroll
        for (int half = 0; half < 2; ++half) {
            int ct = 2 * ks + half;
            float4 bv = *(const float4*)(b2 + ks * 32 + kg * 8 + half * 4);
            float v0 = fmaxf(acc2[ct][0] + bv.x, 0.f), v1 = fmaxf(acc2[ct][1] + bv.y, 0.f);
            float v2 = fmaxf(acc2[ct][2] + bv.z, 0.f), v3 = fmaxf(acc2[ct][3] + bv.w, 0.f);
            h2[ks].u[2 * half]     = pack2bf(v0, v1);
            h2[ks].u[2 * half + 1] = pack2bf(v2, v3);
        }
    }

    // ---- Layer 3 (4 MFMA): canonical W3, h2 as B fragments ----
    f32x4 acc3 = z4;
    #pragma unroll
    for (int ks = 0; ks < 4; ++ks) {
        short8v wf = *(const short8v*)(w3t + m * 128 + ks * 32 + kg * 8);
        acc3 = __builtin_amdgcn_mfma_f32_16x16x32_bf16(wf, h2[ks].v, acc3, 0, 0, 0);
    }
    {   // lane holds o[4kg+r] of element e_loc -> packed 8B store
        uint2 u = { pack2bf(acc3[0], acc3[1]), pack2bf(acc3[2], acc3[3]) };
        *(uint2*)(sO + e_loc * 16 + kg * 4) = u;
    }
    __syncthreads();

    // ---- comb (round-5 proven): thread t -> element t>>2, pair q=t&3 ----
    float w0 = est_w[0];
    float al = fminf(fmaxf(alpha[0], 0.f), 1.f);
    float oma = 1.0f - al;
    {
        int e2 = t >> 2, q = t & 3;
        float* lsp = sLS + e2 * 16 + q * 4;
        float4 lv = *(float4*)lsp;
        const unsigned short* op = sO + e2 * 16;
        float or0 = bf2f(op[2 * q])     + b3[2 * q];
        float or1 = bf2f(op[2 * q + 1]) + b3[2 * q + 1];
        float oi0 = bf2f(op[8 + 2 * q]) + b3[8 + 2 * q];
        float oi1 = bf2f(op[9 + 2 * q]) + b3[9 + 2 * q];
        float4 cb;
        cb.x = al * (lv.x * w0) + oma * fast_tanh(or0);
        cb.y = al * (lv.y * w0) + oma * fast_tanh(oi0);
        cb.z = al * (lv.z * w0) + oma * fast_tanh(or1);
        cb.w = al * (lv.w * w0) + oma * fast_tanh(oi1);
        *(float4*)lsp = cb;
    }
    __syncthreads();

    // ---- epilogue (round-5 proven): 1 KB contiguous per wave-instr ----
    {
        int j = l & 31, half = l >> 5;
        float Ar[32];
        const float4* ap = (const float4*)(Amat + j * 32);
        #pragma unroll
        for (int q4 = 0; q4 < 8; ++q4) {
            float4 v = ap[q4];
            Ar[4 * q4 + 0] = v.x; Ar[4 * q4 + 1] = v.y;
            Ar[4 * q4 + 2] = v.z; Ar[4 * q4 + 3] = v.w;
        }
        #pragma unroll
        for (int it = 0; it < 8; ++it) {
            int e2 = w * 16 + 2 * it + half;
            long gelem = (long)blockIdx.x * 64 + e2;
            const float* lsp = sLS + e2 * 16;
            float4 C0 = *(const float4*)(lsp + 0), C1 = *(const float4*)(lsp + 4);
            float4 C2 = *(const float4*)(lsp + 8), C3 = *(const float4*)(lsp + 12);
            float cr[8] = { C0.x, C0.z, C1.x, C1.z, C2.x, C2.z, C3.x, C3.z };
            float ci[8] = { C0.y, C0.w, C1.y, C1.w, C2.y, C2.w, C3.y, C3.w };
            float hr0 = 0.f, hi0 = 0.f, hr1 = 0.f, hi1 = 0.f;
            #pragma unroll
            for (int p = 0; p < 8; ++p) {
                float a0r = Ar[2 * p], a0i = Ar[2 * p + 1];
                float a1r = Ar[16 + 2 * p], a1i = Ar[17 + 2 * p];
                hr0 += cr[p] * a0r - ci[p] * a0i;
                hi0 += cr[p] * a0i + ci[p] * a0r;
                hr1 += cr[p] * a1r - ci[p] * a1i;
                hi1 += cr[p] * a1i + ci[p] * a1r;
            }
            if (gelem < B) {
                float4 st = { hr0, hi0, hr1, hi1 };
                *(float4*)(out + gelem * 128 + j * 4) = st;
            }
        }
    }
}

extern "C" void kernel_launch(void* const* d_in, const int* in_sizes, int n_in,
                              void* d_out, int out_size, void* d_ws, size_t ws_size,
                              hipStream_t stream) {
    const float* Y             = (const float*)d_in[0];
    const float* Xp            = (const float*)d_in[1];
    const int*   pilot_pos     = (const int*)d_in[2];
    const float* W1            = (const float*)d_in[3];
    const float* b1            = (const float*)d_in[4];
    const float* W2            = (const float*)d_in[5];
    const float* b2            = (const float*)d_in[6];
    const float* W3            = (const float*)d_in[7];
    const float* b3            = (const float*)d_in[8];
    const float* est_w         = (const float*)d_in[9];
    const float* alpha         = (const float*)d_in[10];
    const float* decay_param   = (const float*)d_in[11];
    const float* window_logits = (const float*)d_in[12];
    float* out = (float*)d_out;
    char* ws = (char*)d_ws;

    int B = in_sizes[0] / 128;

    hipLaunchKernelGGL(ce_prep_kernel, dim3(1), dim3(256), 0, stream,
                       pilot_pos, decay_param, window_logits, W1, W2, W3, ws);
    int grid = (B + 63) / 64;
    hipLaunchKernelGGL(ce_main, dim3(grid), dim3(256), 0, stream,
                       Y, Xp, pilot_pos, b1, b2, b3, est_w, alpha,
                       ws, out, B);
}